// Round 3
// baseline (1072.984 us; speedup 1.0000x reference)
//
#include <hip/hip_runtime.h>
#include <hip/hip_bf16.h>

// Problem dims
#define B_ 1024
#define I_ 512
#define O_ 512
#define M_ 8
#define R_ 512
#define A_ 16
#define D_ 128   // M_*A_
#define NLEV 11  // squaring levels: k = 2^j, j=0..11

using bf16 = __hip_bfloat16;

// ---------------------------------------------------------------------------
// Generic 64x64-tile fp32 GEMM, K-chunk 16, 256 threads, 4x4 acc/thread.
// ---------------------------------------------------------------------------
template<class FA, class FB, class FC>
__global__ __launch_bounds__(256) void gemm64(FA fa, FB fb, FC fc, int Ktot){
  __shared__ __align__(16) float As[16][64];   // As[k][row]
  __shared__ __align__(16) float Bs[16][64];   // Bs[k][col]
  const int t  = threadIdx.x;
  const int tx = t & 15, ty = t >> 4;
  const int row0 = blockIdx.y * 64, col0 = blockIdx.x * 64;
  const int rA = t >> 2, kA = (t & 3) * 4;     // A-load: 4 consecutive k
  const int kB = t >> 4, jB = (t & 15) * 4;    // B-load: 4 consecutive cols
  float acc[4][4] = {};
  for (int k0 = 0; k0 < Ktot; k0 += 16){
    #pragma unroll
    for (int l = 0; l < 4; ++l) As[kA + l][rA] = fa(row0 + rA, k0 + kA + l);
    #pragma unroll
    for (int l = 0; l < 4; ++l) Bs[kB][jB + l] = fb(k0 + kB, col0 + jB + l);
    __syncthreads();
    #pragma unroll
    for (int kk = 0; kk < 16; ++kk){
      const float4 a4 = *reinterpret_cast<const float4*>(&As[kk][ty * 4]);
      const float4 b4 = *reinterpret_cast<const float4*>(&Bs[kk][tx * 4]);
      const float av[4] = {a4.x, a4.y, a4.z, a4.w};
      const float bv[4] = {b4.x, b4.y, b4.z, b4.w};
      #pragma unroll
      for (int ii = 0; ii < 4; ++ii)
        #pragma unroll
        for (int jj = 0; jj < 4; ++jj)
          acc[ii][jj] = fmaf(av[ii], bv[jj], acc[ii][jj]);
    }
    __syncthreads();
  }
  #pragma unroll
  for (int ii = 0; ii < 4; ++ii)
    #pragma unroll
    for (int jj = 0; jj < 4; ++jj)
      fc(row0 + ty * 4 + ii, col0 + tx * 4 + jj, acc[ii][jj]);
}

// ------------------------- operand functors (fp32 everywhere) ---------------
struct AXi  { const float* p; __device__ float operator()(int r, int k) const { return p[r * I_ + k]; } };
// Wq/Wk/Wv layout [M, 512, A]: col c=(m,a) -> p[m*8192 + k*16 + a]
struct BWx  { const float* p; __device__ float operator()(int k, int c) const { return p[(c >> 4) * (512 * A_) + k * A_ + (c & 15)]; } };
struct CQ   { float* p; __device__ void operator()(int r, int c, float v) const { p[r * D_ + c] = v; } };
// rows r=(b,n) of Si [B*M, R]
struct ASi  { const float* p; __device__ float operator()(int r, int k) const { return p[r * R_ + k]; } };
// K/V stored [B, M, N, A]
struct CKV  { float* p; __device__ void operator()(int r, int c, float v) const {
  int b = r >> 3, n = r & 7, m = c >> 4, a = c & 15;
  p[b * 1024 + m * 128 + n * 16 + a] = v; } };
// pre GEMM: A = [Ui | (sr/rho)*Si], B = [Win ; W], per unit m = blockIdx.z
struct APre { const float* ui; const float* si; const float* sc; __device__ float operator()(int r, int k) const {
  int m = blockIdx.z;
  if (k < D_) return ui[(r * M_ + m) * D_ + k];
  return sc[m] * si[(r * M_ + m) * R_ + (k - D_)]; } };
struct BPre { const float* win; const float* w; __device__ float operator()(int k, int c) const {
  int m = blockIdx.z;
  if (k < D_) return win[m * (D_ * R_) + k * R_ + c];
  return w[m * (R_ * R_) + (k - D_) * R_ + c]; } };
struct CPre { float* p; __device__ void operator()(int r, int c, float v) const {
  p[(r * M_ + blockIdx.z) * R_ + c] = v; } };
// Yi GEMM: A = Snew (fp32, from d_out tail), B = Wout (fp32)
struct AYi  { const float* p; __device__ float operator()(int r, int k) const { return p[r * 4096 + k]; } };
struct BYi  { const float* p; __device__ float operator()(int k, int c) const { return p[k * O_ + c]; } };
struct CYi  { float* p; __device__ void operator()(int r, int c, float v) const { p[r * O_ + c] = v; } };

// ---------------------------------------------------------------------------
// Eigen chain: repeated squaring with Frobenius normalization.
// L_j = ln||W^(2^j)||_F tracked exactly; lnrho from deep second difference.
// ---------------------------------------------------------------------------
__global__ void k_init(float* norm2){
  int t = threadIdx.x;
  if (t < 8 * (NLEV + 1)) norm2[t] = 0.f;
}

__global__ __launch_bounds__(256) void k_normw(const float* W, float* norm2){
  __shared__ float red[256];
  const int u = blockIdx.y, t = threadIdx.x;
  const float* Wm = W + (size_t)u * (R_ * R_);
  const int base = blockIdx.x * 8192;
  float s = 0.f;
  for (int e = 0; e < 32; ++e){ float x = Wm[base + e * 256 + t]; s = fmaf(x, x, s); }
  red[t] = s; __syncthreads();
  for (int o = 128; o > 0; o >>= 1){ if (t < o) red[t] += red[t + o]; __syncthreads(); }
  if (t == 0) atomicAdd(&norm2[u], red[0]);
}

__global__ __launch_bounds__(256) void k_finalize0(const float* W, const float* norm2,
                                                   float* Acur, float* Lrun, float* Lhist){
  const int u = blockIdx.y, t = threadIdx.x;
  const float n2 = norm2[u];
  const float sc = 1.f / sqrtf(n2);
  const int base = u * 262144 + blockIdx.x * 1024;
  for (int e = 0; e < 4; ++e){ int idx = base + e * 256 + t; Acur[idx] = W[idx] * sc; }
  if (blockIdx.x == 0 && t == 0){ float L = 0.5f * logf(n2); Lrun[u] = L; Lhist[u] = L; }
}

// P = A*A per unit (A normalized), plus reduced sum-of-squares -> norm2[level][u]
__global__ __launch_bounds__(256) void k_gemm_sq(const float* Acur, float* P, float* norm2, int level){
  __shared__ __align__(16) float As[16][64];
  __shared__ __align__(16) float Bs[16][64];
  const int u = blockIdx.z;
  const float* Am = Acur + (size_t)u * (R_ * R_);
  const int t  = threadIdx.x;
  const int tx = t & 15, ty = t >> 4;
  const int row0 = blockIdx.y * 64, col0 = blockIdx.x * 64;
  const int rA = t >> 2, kA = (t & 3) * 4;
  const int kB = t >> 4, jB = (t & 15) * 4;
  float acc[4][4] = {};
  for (int k0 = 0; k0 < R_; k0 += 16){
    #pragma unroll
    for (int l = 0; l < 4; ++l) As[kA + l][rA] = Am[(row0 + rA) * R_ + k0 + kA + l];
    #pragma unroll
    for (int l = 0; l < 4; ++l) Bs[kB][jB + l] = Am[(k0 + kB) * R_ + col0 + jB + l];
    __syncthreads();
    #pragma unroll
    for (int kk = 0; kk < 16; ++kk){
      const float4 a4 = *reinterpret_cast<const float4*>(&As[kk][ty * 4]);
      const float4 b4 = *reinterpret_cast<const float4*>(&Bs[kk][tx * 4]);
      const float av[4] = {a4.x, a4.y, a4.z, a4.w};
      const float bv[4] = {b4.x, b4.y, b4.z, b4.w};
      #pragma unroll
      for (int ii = 0; ii < 4; ++ii)
        #pragma unroll
        for (int jj = 0; jj < 4; ++jj)
          acc[ii][jj] = fmaf(av[ii], bv[jj], acc[ii][jj]);
    }
    __syncthreads();
  }
  float s = 0.f;
  float* Pm = P + (size_t)u * (R_ * R_);
  #pragma unroll
  for (int ii = 0; ii < 4; ++ii)
    #pragma unroll
    for (int jj = 0; jj < 4; ++jj){
      float v = acc[ii][jj];
      Pm[(row0 + ty * 4 + ii) * R_ + col0 + tx * 4 + jj] = v;
      s = fmaf(v, v, s);
    }
  float* red = &As[0][0];
  red[t] = s; __syncthreads();
  for (int o = 128; o > 0; o >>= 1){ if (t < o) red[t] += red[t + o]; __syncthreads(); }
  if (t == 0) atomicAdd(&norm2[level * 8 + u], red[0]);
}

__global__ __launch_bounds__(256) void k_finalize(const float* P, const float* norm2,
                                                  float* Acur, float* Lrun, float* Lhist, int level){
  const int u = blockIdx.y, t = threadIdx.x;
  const float n2 = norm2[level * 8 + u];
  const float sc = 1.f / sqrtf(n2);
  const int base = u * 262144 + blockIdx.x * 1024;
  for (int e = 0; e < 4; ++e){ int idx = base + e * 256 + t; Acur[idx] = P[idx] * sc; }
  if (blockIdx.x == 0 && t == 0){
    float L = 2.f * Lrun[u] + 0.5f * logf(n2);
    Lrun[u] = L; Lhist[level * 8 + u] = L;
  }
}

// lnrho = (L11 - 2*L10 + L9)/512 : second difference at log2-spaced k cancels
// both the constant and any b*ln(k) drift exactly; at k=2048 sub-dominant
// modes are decayed, so the residual is small.
__global__ void k_rho(const float* Lhist, const float* sr, float* sscale){
  int t = threadIdx.x;
  if (t < 8){
    float L9  = Lhist[9  * 8 + t];
    float L10 = Lhist[10 * 8 + t];
    float L11 = Lhist[11 * 8 + t];
    float lnr = (L11 - 2.f * L10 + L9) * (1.f / 512.f);
    sscale[t] = sr[t] / expf(lnr);
  }
}

// ---------------------------------------------------------------------------
// Attention: one wave per (b,m). lane = q*8+n.
// ---------------------------------------------------------------------------
__global__ __launch_bounds__(256) void k_attn(const float* Q, const float* K, const float* V, float* Ui){
  __shared__ float sQ[4][128], sK[4][128], sV[4][128], sA[4][64];
  const int wib = threadIdx.x >> 6, lane = threadIdx.x & 63;
  const int w = blockIdx.x * 4 + wib;
  const int b = w >> 3, m = w & 7;
  for (int e = lane; e < 128; e += 64){
    sQ[wib][e] = Q[b * 128 + e];
    sK[wib][e] = K[b * 1024 + m * 128 + e];
    sV[wib][e] = V[b * 1024 + m * 128 + e];
  }
  __syncthreads();
  const int q = lane >> 3, n = lane & 7;
  float s = 0.f;
  #pragma unroll
  for (int a = 0; a < 16; ++a) s = fmaf(sQ[wib][q * 16 + a], sK[wib][n * 16 + a], s);
  float mx = s;
  for (int d2 = 1; d2 < 8; d2 <<= 1) mx = fmaxf(mx, __shfl_xor(mx, d2, 64));
  float p = expf(s - mx);
  float sm = p;
  for (int d2 = 1; d2 < 8; d2 <<= 1) sm += __shfl_xor(sm, d2, 64);
  // softmax, then divide by sqrt(D)=sqrt(128) (division AFTER softmax per source)
  float ai = p / (sm * 11.313708498984761f);
  sA[wib][q * 8 + n] = ai;
  __syncthreads();
  for (int e = lane; e < 128; e += 64){
    int q2 = e >> 4, a2 = e & 15;
    float acc = 0.f;
    #pragma unroll
    for (int n2 = 0; n2 < 8; ++n2) acc = fmaf(sA[wib][q2 * 8 + n2], sV[wib][n2 * 16 + a2], acc);
    Ui[(b * 8 + m) * 128 + e] = acc;
  }
}

// Snew = (1-lr)*Si + lr*tanh(pre + bias); write fp32 into d_out Snew region
__global__ __launch_bounds__(256) void k_final_ew(const float* pre, const float* bias, const float* lr,
                                                  const float* Si, float* outSnew){
  const int t = threadIdx.x;
  for (int e = 0; e < 4; ++e){
    int idx = blockIdx.x * 1024 + e * 256 + t;
    int m = (idx >> 9) & 7, r = idx & 511;
    float v  = pre[idx] + bias[m * 512 + r];
    float tt = tanhf(v);
    float l  = lr[m];
    float sn = (1.f - l) * Si[idx] + l * tt;
    outSnew[idx] = sn;
  }
}

// ---------------------------------------------------------------------------
extern "C" void kernel_launch(void* const* d_in, const int* in_sizes, int n_in,
                              void* d_out, int out_size, void* d_ws, size_t ws_size,
                              hipStream_t stream) {
  const float* Xi   = (const float*)d_in[0];
  const float* Si   = (const float*)d_in[1];
  const float* Wq   = (const float*)d_in[2];
  const float* Wk   = (const float*)d_in[3];
  const float* Wv   = (const float*)d_in[4];
  const float* Wout = (const float*)d_in[5];
  const float* W    = (const float*)d_in[6];
  const float* Win  = (const float*)d_in[7];
  const float* bias = (const float*)d_in[8];
  const float* sr   = (const float*)d_in[9];
  const float* lr   = (const float*)d_in[10];

  float* ws = (float*)d_ws;
  // ws layout (floats)
  float* Acur  = ws + 0;         // 2,097,152
  float* P     = ws + 2097152;   // eigen product; 'pre' later reuses this region
  float* preb  = P;              // 4,194,304 (pre[B,M,R])
  float* Qb    = ws + 6291456;   // 131,072
  float* Kb    = ws + 6422528;   // 1,048,576
  float* Vb    = ws + 7471104;   // 1,048,576
  float* Uib   = ws + 8519680;   // 1,048,576
  float* norm2 = ws + 9568256;   // 96 (levels 0..11 x 8 units)
  float* Lhist = ws + 9568352;   // 96
  float* Lrun  = ws + 9568448;   // 8
  float* sscal = ws + 9568456;   // 8
  // total ~9,568,464 floats = 38.3 MB

  float* outYi   = (float*)d_out;              // [1024,512]  fp32
  float* outSnew = (float*)d_out + 524288;     // [1024,8,512] fp32

  // ---- spectral radius chain: A0=W/||W||F, NLEV squarings with normalization
  k_init<<<1, 128, 0, stream>>>(norm2);
  k_normw<<<dim3(32, 8), 256, 0, stream>>>(W, norm2);
  k_finalize0<<<dim3(256, 8), 256, 0, stream>>>(W, norm2, Acur, Lrun, Lhist);
  for (int j = 1; j <= NLEV; ++j){
    k_gemm_sq<<<dim3(8, 8, 8), 256, 0, stream>>>(Acur, P, norm2, j);
    k_finalize<<<dim3(256, 8), 256, 0, stream>>>(P, norm2, Acur, Lrun, Lhist, j);
  }
  k_rho<<<1, 64, 0, stream>>>(Lhist, sr, sscal);

  // ---- main pipeline ----
  gemm64<<<dim3(2, 16), 256, 0, stream>>>(AXi{Xi}, BWx{Wq}, CQ{Qb}, 512);
  gemm64<<<dim3(2, 128), 256, 0, stream>>>(ASi{Si}, BWx{Wk}, CKV{Kb}, 512);
  gemm64<<<dim3(2, 128), 256, 0, stream>>>(ASi{Si}, BWx{Wv}, CKV{Vb}, 512);
  k_attn<<<2048, 256, 0, stream>>>(Qb, Kb, Vb, Uib);
  gemm64<<<dim3(8, 16, 8), 256, 0, stream>>>(APre{Uib, Si, sscal}, BPre{Win, W}, CPre{preb}, 640);
  k_final_ew<<<4096, 256, 0, stream>>>(preb, bias, lr, Si, outSnew);
  gemm64<<<dim3(8, 16), 256, 0, stream>>>(AYi{outSnew}, BYi{Wout}, CYi{outYi}, 4096);
}

// Round 4
// 711.226 us; speedup vs baseline: 1.5086x; 1.5086x over previous
//
#include <hip/hip_runtime.h>
#include <hip/hip_bf16.h>

// Problem dims
#define B_ 1024
#define I_ 512
#define O_ 512
#define M_ 8
#define R_ 512
#define A_ 16
#define D_ 128   // M_*A_
#define NLEV 11  // squaring levels: k = 2^j, j=0..11

using bf16 = __hip_bfloat16;
typedef __attribute__((ext_vector_type(8))) short bf16x8;
typedef __attribute__((ext_vector_type(4))) float f32x4;

__device__ __forceinline__ short f2b(float x){
  __hip_bfloat16 h = __float2bfloat16(x);
  union { __hip_bfloat16 h; short s; } u; u.h = h; return u.s;
}

// ---------------------------------------------------------------------------
// MFMA bf16 GEMM template: 64x64 tile, BK=32, 256 threads (4 waves, each wave
// a 32x32 quadrant via 2x2 of 16x16x32 MFMA). Operands loaded via functors
// (fp32 sources), converted to bf16 in LDS. LDS layout k-contiguous with +8
// pad (row stride 40 shorts = 80 B -> 16B-aligned b128, 2-way bank alias=free).
// SKL: log2 of split-K factor (blockIdx.z low bits select K segment).
// ---------------------------------------------------------------------------
template<int SKL, class FA, class FB, class FC>
__global__ __launch_bounds__(256) void gemm_mfma(FA fa, FB fb, FC fc, int Ktot){
  __shared__ __align__(16) short As[64][40];   // [m][k]
  __shared__ __align__(16) short Bs[64][40];   // [n][k]  (B transposed)
  const int t = threadIdx.x;
  const int wv = t >> 6, lane = t & 63;
  const int row0 = blockIdx.y * 64, col0 = blockIdx.x * 64;
  const int kseg = Ktot >> SKL;
  const int kbeg = (blockIdx.z & ((1 << SKL) - 1)) * kseg;
  const int sr = t >> 2, sk = (t & 3) * 8;       // staging: 8 consecutive k
  const int wr = (wv >> 1) * 32, wc = (wv & 1) * 32;
  const int fm = lane & 15, fq = lane >> 4;      // fragment indices
  f32x4 zz = {0.f, 0.f, 0.f, 0.f};
  f32x4 acc[2][2] = {{zz, zz}, {zz, zz}};
  for (int k0 = 0; k0 < kseg; k0 += 32){
    float av[8], bv[8];
    #pragma unroll
    for (int j = 0; j < 8; ++j) av[j] = fa(row0 + sr, kbeg + k0 + sk + j);
    #pragma unroll
    for (int j = 0; j < 8; ++j) bv[j] = fb(kbeg + k0 + sk + j, col0 + sr);
    __syncthreads();                 // prev-iter frag reads done
    bf16x8 pa, pb;
    #pragma unroll
    for (int j = 0; j < 8; ++j){ pa[j] = f2b(av[j]); pb[j] = f2b(bv[j]); }
    *(bf16x8*)&As[sr][sk] = pa;
    *(bf16x8*)&Bs[sr][sk] = pb;
    __syncthreads();
    bf16x8 af[2], bf[2];
    #pragma unroll
    for (int i = 0; i < 2; ++i){
      af[i] = *(const bf16x8*)&As[wr + i * 16 + fm][fq * 8];
      bf[i] = *(const bf16x8*)&Bs[wc + i * 16 + fm][fq * 8];
    }
    #pragma unroll
    for (int i = 0; i < 2; ++i)
      #pragma unroll
      for (int j = 0; j < 2; ++j)
        acc[i][j] = __builtin_amdgcn_mfma_f32_16x16x32_bf16(af[i], bf[j], acc[i][j], 0, 0, 0);
  }
  // C/D layout: col = lane&15, row = (lane>>4)*4 + reg
  #pragma unroll
  for (int i = 0; i < 2; ++i)
    #pragma unroll
    for (int j = 0; j < 2; ++j)
      #pragma unroll
      for (int r = 0; r < 4; ++r)
        fc(row0 + wr + i * 16 + fq * 4 + r, col0 + wc + j * 16 + fm, acc[i][j][r]);
}

// ------------------------- operand functors (fp32 sources) ------------------
struct AXi  { const float* p; __device__ float operator()(int r, int k) const { return p[r * I_ + k]; } };
// Wq/Wk/Wv layout [M, 512, A]: col c=(m,a) -> p[m*8192 + k*16 + a]
struct BWx  { const float* p; __device__ float operator()(int k, int c) const { return p[(c >> 4) * (512 * A_) + k * A_ + (c & 15)]; } };
struct CQ   { float* p; __device__ void operator()(int r, int c, float v) const { p[r * D_ + c] = v; } };
struct ASi  { const float* p; __device__ float operator()(int r, int k) const { return p[r * R_ + k]; } };
// K/V stored [B, M, N, A]
struct CKV  { float* p; __device__ void operator()(int r, int c, float v) const {
  int b = r >> 3, n = r & 7, m = c >> 4, a = c & 15;
  p[b * 1024 + m * 128 + n * 16 + a] = v; } };
// pre GEMM: A = [Ui | (sr/rho)*Si], B = [Win ; W], unit m = blockIdx.z (SKL=0)
struct APre { const float* ui; const float* si; const float* sc; __device__ float operator()(int r, int k) const {
  int m = blockIdx.z;
  if (k < D_) return ui[(r * M_ + m) * D_ + k];
  return sc[m] * si[(r * M_ + m) * R_ + (k - D_)]; } };
struct BPre { const float* win; const float* w; __device__ float operator()(int k, int c) const {
  int m = blockIdx.z;
  if (k < D_) return win[m * (D_ * R_) + k * R_ + c];
  return w[m * (R_ * R_) + (k - D_) * R_ + c]; } };
struct CPre { float* p; __device__ void operator()(int r, int c, float v) const {
  p[(r * M_ + blockIdx.z) * R_ + c] = v; } };
// Yi GEMM (split-K=4): A = Snew fp32 (d_out tail), B = Wout; atomic epilogue
struct AYi  { const float* p; __device__ float operator()(int r, int k) const { return p[r * 4096 + k]; } };
struct BYi  { const float* p; __device__ float operator()(int k, int c) const { return p[k * O_ + c]; } };
struct CYiA { float* p; __device__ void operator()(int r, int c, float v) const { atomicAdd(&p[r * O_ + c], v); } };

// ---------------------------------------------------------------------------
// Eigen chain: normalized repeated squaring, MFMA. Normalization fused into
// staging load (scale = rsqrt(norm2[lev-1])). Writes P fp32 + sum-of-squares.
// ---------------------------------------------------------------------------
__global__ __launch_bounds__(256) void k_sq_mfma(const float* src, float* dst,
                                                 float* norm2, int lev){
  __shared__ __align__(16) short As[64][40];
  __shared__ __align__(16) short Bs[64][40];
  const int u = blockIdx.z;
  const float s = rsqrtf(norm2[(lev - 1) * 8 + u]);
  const float* Sm = src + (size_t)u * (R_ * R_);
  float* Dm = dst + (size_t)u * (R_ * R_);
  const int t = threadIdx.x;
  const int wv = t >> 6, lane = t & 63;
  const int row0 = blockIdx.y * 64, col0 = blockIdx.x * 64;
  const int sr = t >> 2, sk = (t & 3) * 8;
  const int wr = (wv >> 1) * 32, wc = (wv & 1) * 32;
  const int fm = lane & 15, fq = lane >> 4;
  f32x4 zz = {0.f, 0.f, 0.f, 0.f};
  f32x4 acc[2][2] = {{zz, zz}, {zz, zz}};
  for (int k0 = 0; k0 < R_; k0 += 32){
    float av[8], bv[8];
    #pragma unroll
    for (int j = 0; j < 8; ++j) av[j] = Sm[(row0 + sr) * R_ + k0 + sk + j] * s;
    #pragma unroll
    for (int j = 0; j < 8; ++j) bv[j] = Sm[(k0 + sk + j) * R_ + col0 + sr] * s;
    __syncthreads();
    bf16x8 pa, pb;
    #pragma unroll
    for (int j = 0; j < 8; ++j){ pa[j] = f2b(av[j]); pb[j] = f2b(bv[j]); }
    *(bf16x8*)&As[sr][sk] = pa;
    *(bf16x8*)&Bs[sr][sk] = pb;
    __syncthreads();
    bf16x8 af[2], bf[2];
    #pragma unroll
    for (int i = 0; i < 2; ++i){
      af[i] = *(const bf16x8*)&As[wr + i * 16 + fm][fq * 8];
      bf[i] = *(const bf16x8*)&Bs[wc + i * 16 + fm][fq * 8];
    }
    #pragma unroll
    for (int i = 0; i < 2; ++i)
      #pragma unroll
      for (int j = 0; j < 2; ++j)
        acc[i][j] = __builtin_amdgcn_mfma_f32_16x16x32_bf16(af[i], bf[j], acc[i][j], 0, 0, 0);
  }
  float ss = 0.f;
  #pragma unroll
  for (int i = 0; i < 2; ++i)
    #pragma unroll
    for (int j = 0; j < 2; ++j)
      #pragma unroll
      for (int r = 0; r < 4; ++r){
        float v = acc[i][j][r];
        Dm[(row0 + wr + i * 16 + fq * 4 + r) * R_ + col0 + wc + j * 16 + fm] = v;
        ss = fmaf(v, v, ss);
      }
  #pragma unroll
  for (int o = 32; o > 0; o >>= 1) ss += __shfl_xor(ss, o, 64);
  if (lane == 0) atomicAdd(&norm2[lev * 8 + u], ss);
}

__global__ void k_init(float* norm2){
  int t = threadIdx.x;
  if (t < 8 * (NLEV + 1)) norm2[t] = 0.f;
}

__global__ __launch_bounds__(256) void k_zero(float* p){
  const int t = threadIdx.x;
  #pragma unroll
  for (int e = 0; e < 4; ++e) p[blockIdx.x * 1024 + e * 256 + t] = 0.f;
}

__global__ __launch_bounds__(256) void k_normw(const float* W, float* norm2){
  __shared__ float red[256];
  const int u = blockIdx.y, t = threadIdx.x;
  const float* Wm = W + (size_t)u * (R_ * R_);
  const int base = blockIdx.x * 8192;
  float s = 0.f;
  for (int e = 0; e < 32; ++e){ float x = Wm[base + e * 256 + t]; s = fmaf(x, x, s); }
  red[t] = s; __syncthreads();
  for (int o = 128; o > 0; o >>= 1){ if (t < o) red[t] += red[t + o]; __syncthreads(); }
  if (t == 0) atomicAdd(&norm2[u], red[0]);
}

// L_j = 2 L_{j-1} + 0.5 ln n2_j ; lnrho = (L11 - 2 L10 + L9)/512
// (weights cancel the constant and the b*j drift of the edge-annulus model)
__global__ void k_rho(const float* norm2, const float* sr, float* sscale){
  int t = threadIdx.x;
  if (t < 8){
    float L = 0.5f * logf(norm2[t]);
    float L9 = 0.f, L10 = 0.f, L11 = 0.f;
    for (int j = 1; j <= NLEV; ++j){
      L = 2.f * L + 0.5f * logf(norm2[j * 8 + t]);
      if (j == 9)  L9  = L;
      if (j == 10) L10 = L;
      if (j == 11) L11 = L;
    }
    float lnr = (L11 - 2.f * L10 + L9) * (1.f / 512.f);
    sscale[t] = sr[t] / expf(lnr);
  }
}

// ---------------------------------------------------------------------------
// Attention: one wave per (b,m). lane = q*8+n. fp32 (cheap, softmax-sensitive)
// ---------------------------------------------------------------------------
__global__ __launch_bounds__(256) void k_attn(const float* Q, const float* K, const float* V, float* Ui){
  __shared__ float sQ[4][128], sK[4][128], sV[4][128], sA[4][64];
  const int wib = threadIdx.x >> 6, lane = threadIdx.x & 63;
  const int w = blockIdx.x * 4 + wib;
  const int b = w >> 3, m = w & 7;
  for (int e = lane; e < 128; e += 64){
    sQ[wib][e] = Q[b * 128 + e];
    sK[wib][e] = K[b * 1024 + m * 128 + e];
    sV[wib][e] = V[b * 1024 + m * 128 + e];
  }
  __syncthreads();
  const int q = lane >> 3, n = lane & 7;
  float s = 0.f;
  #pragma unroll
  for (int a = 0; a < 16; ++a) s = fmaf(sQ[wib][q * 16 + a], sK[wib][n * 16 + a], s);
  float mx = s;
  for (int d2 = 1; d2 < 8; d2 <<= 1) mx = fmaxf(mx, __shfl_xor(mx, d2, 64));
  float p = expf(s - mx);
  float sm = p;
  for (int d2 = 1; d2 < 8; d2 <<= 1) sm += __shfl_xor(sm, d2, 64);
  float ai = p / (sm * 11.313708498984761f);   // softmax then /sqrt(128)
  sA[wib][q * 8 + n] = ai;
  __syncthreads();
  for (int e = lane; e < 128; e += 64){
    int q2 = e >> 4, a2 = e & 15;
    float acc = 0.f;
    #pragma unroll
    for (int n2 = 0; n2 < 8; ++n2) acc = fmaf(sA[wib][q2 * 8 + n2], sV[wib][n2 * 16 + a2], acc);
    Ui[(b * 8 + m) * 128 + e] = acc;
  }
}

// Snew = (1-lr)*Si + lr*tanh(pre + bias)
__global__ __launch_bounds__(256) void k_final_ew(const float* pre, const float* bias, const float* lr,
                                                  const float* Si, float* outSnew){
  const int t = threadIdx.x;
  for (int e = 0; e < 4; ++e){
    int idx = blockIdx.x * 1024 + e * 256 + t;
    int m = (idx >> 9) & 7, r = idx & 511;
    float v  = pre[idx] + bias[m * 512 + r];
    float tt = tanhf(v);
    float l  = lr[m];
    outSnew[idx] = (1.f - l) * Si[idx] + l * tt;
  }
}

// ---------------------------------------------------------------------------
extern "C" void kernel_launch(void* const* d_in, const int* in_sizes, int n_in,
                              void* d_out, int out_size, void* d_ws, size_t ws_size,
                              hipStream_t stream) {
  const float* Xi   = (const float*)d_in[0];
  const float* Si   = (const float*)d_in[1];
  const float* Wq   = (const float*)d_in[2];
  const float* Wk   = (const float*)d_in[3];
  const float* Wv   = (const float*)d_in[4];
  const float* Wout = (const float*)d_in[5];
  const float* W    = (const float*)d_in[6];
  const float* Win  = (const float*)d_in[7];
  const float* bias = (const float*)d_in[8];
  const float* sr   = (const float*)d_in[9];
  const float* lr   = (const float*)d_in[10];

  float* ws = (float*)d_ws;
  float* Pa    = ws + 0;         // 2,097,152 (8 MB)
  float* Pb    = ws + 2097152;   // 2,097,152
  float* preb  = ws + 0;         // 4,194,304 — aliases Pa+Pb, used after chain
  float* Qb    = ws + 4194304;   // 131,072
  float* Kb    = ws + 4325376;   // 1,048,576
  float* Vb    = ws + 5373952;   // 1,048,576
  float* Uib   = ws + 6422528;   // 1,048,576
  float* norm2 = ws + 7471104;   // 96
  float* sscal = ws + 7471200;   // 8
  // total ~29.9 MB (R3 proved 38.3 MB fits)

  float* outYi   = (float*)d_out;            // [1024,512]
  float* outSnew = (float*)d_out + 524288;   // [1024,8,512]

  // ---- spectral radius chain (normalize fused into staging) ----
  k_init<<<1, 128, 0, stream>>>(norm2);
  k_zero<<<512, 256, 0, stream>>>(outYi);    // for split-K atomic epilogue
  k_normw<<<dim3(32, 8), 256, 0, stream>>>(W, norm2);
  {
    const float* src = W; float* dst = Pa;
    for (int j = 1; j <= NLEV; ++j){
      k_sq_mfma<<<dim3(8, 8, 8), 256, 0, stream>>>(src, dst, norm2, j);
      src = dst; dst = (dst == Pa) ? Pb : Pa;
    }
  }
  k_rho<<<1, 64, 0, stream>>>(norm2, sr, sscal);

  // ---- main pipeline (MFMA bf16) ----
  gemm_mfma<0><<<dim3(2, 16), 256, 0, stream>>>(AXi{Xi}, BWx{Wq}, CQ{Qb}, 512);
  gemm_mfma<0><<<dim3(2, 128), 256, 0, stream>>>(ASi{Si}, BWx{Wk}, CKV{Kb}, 512);
  gemm_mfma<0><<<dim3(2, 128), 256, 0, stream>>>(ASi{Si}, BWx{Wv}, CKV{Vb}, 512);
  k_attn<<<2048, 256, 0, stream>>>(Qb, Kb, Vb, Uib);
  gemm_mfma<0><<<dim3(8, 16, 8), 256, 0, stream>>>(APre{Uib, Si, sscal}, BPre{Win, W}, CPre{preb}, 640);
  k_final_ew<<<4096, 256, 0, stream>>>(preb, bias, lr, Si, outSnew);
  gemm_mfma<2><<<dim3(8, 16, 4), 256, 0, stream>>>(AYi{outSnew}, BYi{Wout}, CYiA{outYi}, 4096);
}